// Round 5
// baseline (184.673 us; speedup 1.0000x reference)
//
#include <hip/hip_runtime.h>
#include <math.h>

#define NN 512
#define CC 32
#define EPSF 1e-8f
#define WS 40   // shorts per LDS row (80 B: 16B-aligned b128 reads, 2-way max conflict = free)

typedef __attribute__((ext_vector_type(8))) short bf16x8;
typedef __attribute__((ext_vector_type(4))) float f32x4;

struct TFNWeights {
    const float* w1[5];
    const float* b1[5];
    const float* w2[5];
    const float* b2[5];
};

// fp32 -> bf16 bits, round-to-nearest-even
__device__ __forceinline__ short f2bf(float f) {
    unsigned u = __float_as_uint(f);
    u += 0x7fffu + ((u >> 16) & 1u);
    return (short)(u >> 16);
}

// One radial MLP (2 layers) for 16 pairs x 32 channels via 4 MFMAs.
// A-frag: row=lane&15, k=8*(lane>>4)+j ; B-frag: col=lane&15, same k
// D-frag: col=lane&15, row=4*(lane>>4)+reg
__device__ __forceinline__ void mlp(const short* wf,      // this filter's wlds base
                                    short* hw,            // this wave's hlds base
                                    const bf16x8 rbfF,
                                    const float b1lo, const float b1hi,
                                    const float b2lo, const float b2hi,
                                    const int q, const int ln,
                                    f32x4& r0, f32x4& r1)
{
    const bf16x8 w1lo = *(const bf16x8*)(wf + ln * WS + q * 8);
    const bf16x8 w1hi = *(const bf16x8*)(wf + (16 + ln) * WS + q * 8);
    f32x4 d0 = { b1lo, b1lo, b1lo, b1lo };
    f32x4 d1 = { b1hi, b1hi, b1hi, b1hi };
    d0 = __builtin_amdgcn_mfma_f32_16x16x32_bf16(rbfF, w1lo, d0, 0, 0, 0);
    d1 = __builtin_amdgcn_mfma_f32_16x16x32_bf16(rbfF, w1hi, d1, 0, 0, 0);
    #pragma unroll
    for (int rr = 0; rr < 4; ++rr) {                 // h transpose (wave-private LDS)
        hw[(q * 4 + rr) * WS + ln]      = f2bf(fmaxf(d0[rr], 0.f));
        hw[(q * 4 + rr) * WS + 16 + ln] = f2bf(fmaxf(d1[rr], 0.f));
    }
    const bf16x8 hF   = *(const bf16x8*)(hw + ln * WS + q * 8);
    const bf16x8 w2lo = *(const bf16x8*)(wf + (32 + ln) * WS + q * 8);
    const bf16x8 w2hi = *(const bf16x8*)(wf + (48 + ln) * WS + q * 8);
    f32x4 e0 = { b2lo, b2lo, b2lo, b2lo };
    f32x4 e1 = { b2hi, b2hi, b2hi, b2hi };
    r0 = __builtin_amdgcn_mfma_f32_16x16x32_bf16(hF, w2lo, e0, 0, 0, 0);
    r1 = __builtin_amdgcn_mfma_f32_16x16x32_bf16(hF, w2hi, e1, 0, 0, 0);
}

__global__ __launch_bounds__(512, 2) void tfn_mfma(
    const float* __restrict__ in0,   // [N,C,1]
    const float* __restrict__ in1,   // [N,C,3]
    const float* __restrict__ in2,   // [N,C,5]
    const float* __restrict__ rbf,   // [N,N,32]
    const float* __restrict__ rij,   // [N,N,3]
    TFNWeights W,
    float* __restrict__ out)
{
    const int a    = blockIdx.x;
    const int tid  = threadIdx.x;
    const int w    = tid >> 6;     // wave 0..7
    const int lane = tid & 63;
    const int q    = lane >> 4;
    const int ln   = lane & 15;

    // 25600 + 10240 + 4096 = 39936 B
    __shared__ short wlds[5 * 2 * 32 * WS];  // weights bf16; ALIASED as `red` after main loop
    __shared__ short hlds[8][16 * WS];       // per-wave h transpose tile
    __shared__ float geom[8][16][8];         // ux,uy,uz,y20..y24 (mask folded)

    // ---- stage weights as bf16 ----
    for (int idx = tid; idx < 10240; idx += 512) {
        const int k = idx & 31, n = (idx >> 5) & 31, layer = (idx >> 10) & 1, f = idx >> 11;
        const float* src = layer ? W.w2[f] : W.w1[f];
        wlds[((f * 2 + layer) * 32 + n) * WS + k] = f2bf(src[n * 32 + k]);
    }
    float b1lo[5], b1hi[5], b2lo[5], b2hi[5];
    #pragma unroll
    for (int f = 0; f < 5; ++f) {
        b1lo[f] = W.b1[f][ln];  b1hi[f] = W.b1[f][16 + ln];
        b2lo[f] = W.b2[f][ln];  b2hi[f] = W.b2[f][16 + ln];
    }
    __syncthreads();

    float acc[2][21];
    #pragma unroll
    for (int h = 0; h < 2; ++h)
        #pragma unroll
        for (int cmp = 0; cmp < 21; ++cmp) acc[h][cmp] = 0.f;

    const size_t rowbase = (size_t)a * NN;
    const float Y2C = 0.28867513459481287f;  // 1/(2*sqrt(3))
    short* hw = &hlds[w][0];

    for (int t = 0; t < 4; ++t) {
        const int b0 = w * 64 + t * 16;

        // ---- per-tile geometry (16 lanes; mask folded; rij is read-once -> nt) ----
        if (lane < 16) {
            const float* rp = rij + (rowbase + b0 + lane) * 3;
            const float x = __builtin_nontemporal_load(rp);
            const float y = __builtin_nontemporal_load(rp + 1);
            const float z = __builtin_nontemporal_load(rp + 2);
            const float d2 = x * x + y * y + z * z;
            const float d  = sqrtf(d2);
            const float m  = (d >= EPSF) ? 1.f : 0.f;
            const float inv = m / (d + EPSF);
            const float ir2 = m / fmaxf(d2, EPSF);
            float* gp = &geom[w][lane][0];
            gp[0] = x * inv; gp[1] = y * inv; gp[2] = z * inv;
            gp[3] = x * y * ir2;
            gp[4] = y * z * ir2;
            gp[5] = (2.f * z * z - x * x - y * y) * (ir2 * Y2C);
            gp[6] = z * x * ir2;
            gp[7] = (x * x - y * y) * (ir2 * 0.5f);
        }

        // ---- rbf A-fragment (read-once stream -> nt), shared by all 5 filters ----
        const float* rsrc = rbf + (rowbase + b0 + ln) * 32 + q * 8;
        const f32x4 ra = __builtin_nontemporal_load((const f32x4*)rsrc);
        const f32x4 rb = __builtin_nontemporal_load((const f32x4*)rsrc + 1);
        bf16x8 rbfF;
        rbfF[0] = f2bf(ra[0]); rbfF[1] = f2bf(ra[1]); rbfF[2] = f2bf(ra[2]); rbfF[3] = f2bf(ra[3]);
        rbfF[4] = f2bf(rb[0]); rbfF[5] = f2bf(rb[1]); rbfF[6] = f2bf(rb[2]); rbfF[7] = f2bf(rb[3]);

        f32x4 r0, r1, r2, r3;

        // ================= filter 0 (scalar): o0_s, o1_s, o2_s =================
        mlp(wlds + 0 * 64 * WS, hw, rbfF, b1lo[0], b1hi[0], b2lo[0], b2hi[0], q, ln, r0, r1);
        #pragma unroll
        for (int rr = 0; rr < 4; ++rr) {
            const int b = b0 + q * 4 + rr;
            #pragma unroll
            for (int h = 0; h < 2; ++h) {
                const int c = ln + h * 16;
                const float s = h ? r1[rr] : r0[rr];
                acc[h][0] = fmaf(s, in0[b * CC + c], acc[h][0]);
                const float* i1p = in1 + (b * CC + c) * 3;
                acc[h][5] = fmaf(s, i1p[0], acc[h][5]);
                acc[h][6] = fmaf(s, i1p[1], acc[h][6]);
                acc[h][7] = fmaf(s, i1p[2], acc[h][7]);
                const float* i2p = in2 + (b * CC + c) * 5;
                #pragma unroll
                for (int j = 0; j < 5; ++j)
                    acc[h][16 + j] = fmaf(s, i2p[j], acc[h][16 + j]);
            }
        }

        // ================= filters 1,2 (use in0): o1_a, o2_a =================
        mlp(wlds + 1 * 64 * WS, hw, rbfF, b1lo[1], b1hi[1], b2lo[1], b2hi[1], q, ln, r0, r1);
        mlp(wlds + 2 * 64 * WS, hw, rbfF, b1lo[2], b1hi[2], b2lo[2], b2hi[2], q, ln, r2, r3);
        #pragma unroll
        for (int rr = 0; rr < 4; ++rr) {
            const int p = q * 4 + rr;
            const int b = b0 + p;
            const float4 g0 = *(const float4*)&geom[w][p][0];
            const float4 g1 = *(const float4*)&geom[w][p][4];
            #pragma unroll
            for (int h = 0; h < 2; ++h) {
                const int c = ln + h * 16;
                const float i0 = in0[b * CC + c];
                const float t01 = (h ? r1[rr] : r0[rr]) * i0;
                acc[h][2] = fmaf(t01, g0.x, acc[h][2]);
                acc[h][3] = fmaf(t01, g0.y, acc[h][3]);
                acc[h][4] = fmaf(t01, g0.z, acc[h][4]);
                const float t02 = (h ? r3[rr] : r2[rr]) * i0;
                acc[h][11] = fmaf(t02, g0.w, acc[h][11]);
                acc[h][12] = fmaf(t02, g1.x, acc[h][12]);
                acc[h][13] = fmaf(t02, g1.y, acc[h][13]);
                acc[h][14] = fmaf(t02, g1.z, acc[h][14]);
                acc[h][15] = fmaf(t02, g1.w, acc[h][15]);
            }
        }

        // ================= filters 3,4 (use in1): o0_b, o1_c =================
        mlp(wlds + 3 * 64 * WS, hw, rbfF, b1lo[3], b1hi[3], b2lo[3], b2hi[3], q, ln, r0, r1);
        mlp(wlds + 4 * 64 * WS, hw, rbfF, b1lo[4], b1hi[4], b2lo[4], b2hi[4], q, ln, r2, r3);
        #pragma unroll
        for (int rr = 0; rr < 4; ++rr) {
            const int p = q * 4 + rr;
            const int b = b0 + p;
            const float4 g0 = *(const float4*)&geom[w][p][0];
            const float ux = g0.x, uy = g0.y, uz = g0.z;
            #pragma unroll
            for (int h = 0; h < 2; ++h) {
                const int c = ln + h * 16;
                const float* i1p = in1 + (b * CC + c) * 3;
                const float i10 = i1p[0], i11 = i1p[1], i12 = i1p[2];
                const float s10 = h ? r1[rr] : r0[rr];
                const float s11 = h ? r3[rr] : r2[rr];
                const float dt = fmaf(uz, i12, fmaf(uy, i11, ux * i10));
                acc[h][1] = fmaf(s10, dt, acc[h][1]);
                const float cx = fmaf(uy, i12, -(uz * i11));
                const float cy = fmaf(uz, i10, -(ux * i12));
                const float cz = fmaf(ux, i11, -(uy * i10));
                acc[h][8]  = fmaf(s11, cx, acc[h][8]);
                acc[h][9]  = fmaf(s11, cy, acc[h][9]);
                acc[h][10] = fmaf(s11, cz, acc[h][10]);
            }
        }
    }

    // ---- cross-wave reduction; reuse wlds space (dead now) as fp32 red buffer ----
    __syncthreads();                       // all waves done reading wlds
    float* red = (float*)wlds;             // [8][21][32] = 21504 B <= 25600 B
    #pragma unroll
    for (int h = 0; h < 2; ++h) {
        #pragma unroll
        for (int cmp = 0; cmp < 21; ++cmp) {
            float v = acc[h][cmp];
            v += __shfl_down(v, 32);
            v += __shfl_down(v, 16);
            if (lane < 16) red[(w * 21 + cmp) * 32 + ln + h * 16] = v;
        }
    }
    __syncthreads();

    const int NC = NN * CC;
    for (int e = tid; e < 21 * 32; e += 512) {
        const int cmp = e >> 5, c = e & 31;
        float s = 0.f;
        #pragma unroll
        for (int g = 0; g < 8; ++g) s += red[(g * 21 + cmp) * 32 + c];
        int idx;
        if (cmp == 0)       idx = a * CC + c;                                       // o0_s
        else if (cmp == 1)  idx = NC + a * CC + c;                                  // o0_b
        else if (cmp < 5)   idx = 2 * NC + (a * CC + c) * 3 + (cmp - 2);            // o1_a
        else if (cmp < 8)   idx = 2 * NC + 3 * NC + (a * CC + c) * 3 + (cmp - 5);   // o1_s
        else if (cmp < 11)  idx = 2 * NC + 6 * NC + (a * CC + c) * 3 + (cmp - 8);   // o1_c
        else if (cmp < 16)  idx = 11 * NC + (a * CC + c) * 5 + (cmp - 11);          // o2_a
        else                idx = 11 * NC + 5 * NC + (a * CC + c) * 5 + (cmp - 16); // o2_s
        out[idx] = s;
    }
}

extern "C" void kernel_launch(void* const* d_in, const int* in_sizes, int n_in,
                              void* d_out, int out_size, void* d_ws, size_t ws_size,
                              hipStream_t stream) {
    const float* in0 = (const float*)d_in[0];
    const float* in1 = (const float*)d_in[1];
    const float* in2 = (const float*)d_in[2];
    const float* rbf = (const float*)d_in[3];
    const float* rij = (const float*)d_in[4];

    TFNWeights W;
    for (int i = 0; i < 5; ++i) {
        W.w1[i] = (const float*)d_in[5 + 4 * i + 0];
        W.b1[i] = (const float*)d_in[5 + 4 * i + 1];
        W.w2[i] = (const float*)d_in[5 + 4 * i + 2];
        W.b2[i] = (const float*)d_in[5 + 4 * i + 3];
    }

    hipLaunchKernelGGL(tfn_mfma, dim3(NN), dim3(512), 0, stream,
                       in0, in1, in2, rbf, rij, W, (float*)d_out);
}

// Round 6
// 173.029 us; speedup vs baseline: 1.0673x; 1.0673x over previous
//
#include <hip/hip_runtime.h>
#include <math.h>

#define NN 512
#define CC 32
#define EPSF 1e-8f
#define WS 40   // shorts per LDS row (80 B: 16B-aligned b128 reads, 2-way max conflict = free)

typedef __attribute__((ext_vector_type(8))) short bf16x8;
typedef __attribute__((ext_vector_type(4))) float f32x4;

// fp32 -> bf16 bits, round-to-nearest-even
__device__ __forceinline__ short f2bf(float f) {
    unsigned u = __float_as_uint(f);
    u += 0x7fffu + ((u >> 16) & 1u);
    return (short)(u >> 16);
}

// One radial MLP (2 layers) for 16 pairs x 32 channels via 4 MFMAs.
// A-frag: row=lane&15, k=8*(lane>>4)+j ; B-frag: col=lane&15, same k
// D-frag: col=lane&15, row=4*(lane>>4)+reg
__device__ __forceinline__ void mlp(const short* wf,      // this filter's wlds base
                                    short* hw,            // this wave's hlds base
                                    const bf16x8 rbfF,
                                    const float b1lo, const float b1hi,
                                    const float b2lo, const float b2hi,
                                    const int q, const int ln,
                                    f32x4& r0, f32x4& r1)
{
    const bf16x8 w1lo = *(const bf16x8*)(wf + ln * WS + q * 8);
    const bf16x8 w1hi = *(const bf16x8*)(wf + (16 + ln) * WS + q * 8);
    f32x4 d0 = { b1lo, b1lo, b1lo, b1lo };
    f32x4 d1 = { b1hi, b1hi, b1hi, b1hi };
    d0 = __builtin_amdgcn_mfma_f32_16x16x32_bf16(rbfF, w1lo, d0, 0, 0, 0);
    d1 = __builtin_amdgcn_mfma_f32_16x16x32_bf16(rbfF, w1hi, d1, 0, 0, 0);
    #pragma unroll
    for (int rr = 0; rr < 4; ++rr) {                 // h transpose (wave-private LDS)
        hw[(q * 4 + rr) * WS + ln]      = f2bf(fmaxf(d0[rr], 0.f));
        hw[(q * 4 + rr) * WS + 16 + ln] = f2bf(fmaxf(d1[rr], 0.f));
    }
    const bf16x8 hF   = *(const bf16x8*)(hw + ln * WS + q * 8);
    const bf16x8 w2lo = *(const bf16x8*)(wf + (32 + ln) * WS + q * 8);
    const bf16x8 w2hi = *(const bf16x8*)(wf + (48 + ln) * WS + q * 8);
    f32x4 e0 = { b2lo, b2lo, b2lo, b2lo };
    f32x4 e1 = { b2hi, b2hi, b2hi, b2hi };
    r0 = __builtin_amdgcn_mfma_f32_16x16x32_bf16(hF, w2lo, e0, 0, 0, 0);
    r1 = __builtin_amdgcn_mfma_f32_16x16x32_bf16(hF, w2hi, e1, 0, 0, 0);
}

// Stage filter F's two 32x32 weight matrices as bf16 into LDS.
// tid in [0,512): n0 = tid>>5 in [0,16), k0 = tid&31; second half via tid+512.
#define STAGE_F(F, W1P, W2P)                                                   \
    {                                                                          \
        const int n0 = tid >> 5, k0 = tid & 31;                                \
        wlds[(((F) * 2 + 0) * 32 + n0) * WS + k0]      = f2bf((W1P)[tid]);     \
        wlds[(((F) * 2 + 0) * 32 + n0 + 16) * WS + k0] = f2bf((W1P)[tid+512]); \
        wlds[(((F) * 2 + 1) * 32 + n0) * WS + k0]      = f2bf((W2P)[tid]);     \
        wlds[(((F) * 2 + 1) * 32 + n0 + 16) * WS + k0] = f2bf((W2P)[tid+512]); \
    }

__global__ __launch_bounds__(512, 2) void tfn_mfma(
    const float* __restrict__ in0,   // [N,C,1]
    const float* __restrict__ in1,   // [N,C,3]
    const float* __restrict__ in2,   // [N,C,5]
    const float* __restrict__ rbf,   // [N,N,32]
    const float* __restrict__ rij,   // [N,N,3]
    const float* __restrict__ w1_0, const float* __restrict__ b1_0,
    const float* __restrict__ w2_0, const float* __restrict__ b2_0,
    const float* __restrict__ w1_1, const float* __restrict__ b1_1,
    const float* __restrict__ w2_1, const float* __restrict__ b2_1,
    const float* __restrict__ w1_2, const float* __restrict__ b1_2,
    const float* __restrict__ w2_2, const float* __restrict__ b2_2,
    const float* __restrict__ w1_3, const float* __restrict__ b1_3,
    const float* __restrict__ w2_3, const float* __restrict__ b2_3,
    const float* __restrict__ w1_4, const float* __restrict__ b1_4,
    const float* __restrict__ w2_4, const float* __restrict__ b2_4,
    float* __restrict__ out)
{
    const int a    = blockIdx.x;
    const int tid  = threadIdx.x;
    const int w    = tid >> 6;     // wave 0..7
    const int lane = tid & 63;
    const int q    = lane >> 4;
    const int ln   = lane & 15;

    // 25600 + 10240 + 4096 = 39936 B
    __shared__ short wlds[5 * 2 * 32 * WS];  // weights bf16; ALIASED as `red` after main loop
    __shared__ short hlds[8][16 * WS];       // per-wave h transpose tile
    __shared__ float geom[8][16][8];         // ux,uy,uz,y20..y24 (mask folded)

    // ---- stage weights as bf16 (all pointer indices compile-time) ----
    STAGE_F(0, w1_0, w2_0)
    STAGE_F(1, w1_1, w2_1)
    STAGE_F(2, w1_2, w2_2)
    STAGE_F(3, w1_3, w2_3)
    STAGE_F(4, w1_4, w2_4)

    const float b1lo0 = b1_0[ln], b1hi0 = b1_0[16 + ln], b2lo0 = b2_0[ln], b2hi0 = b2_0[16 + ln];
    const float b1lo1 = b1_1[ln], b1hi1 = b1_1[16 + ln], b2lo1 = b2_1[ln], b2hi1 = b2_1[16 + ln];
    const float b1lo2 = b1_2[ln], b1hi2 = b1_2[16 + ln], b2lo2 = b2_2[ln], b2hi2 = b2_2[16 + ln];
    const float b1lo3 = b1_3[ln], b1hi3 = b1_3[16 + ln], b2lo3 = b2_3[ln], b2hi3 = b2_3[16 + ln];
    const float b1lo4 = b1_4[ln], b1hi4 = b1_4[16 + ln], b2lo4 = b2_4[ln], b2hi4 = b2_4[16 + ln];
    __syncthreads();

    float acc[2][21];
    #pragma unroll
    for (int h = 0; h < 2; ++h)
        #pragma unroll
        for (int cmp = 0; cmp < 21; ++cmp) acc[h][cmp] = 0.f;

    const size_t rowbase = (size_t)a * NN;
    const float Y2C = 0.28867513459481287f;  // 1/(2*sqrt(3))
    short* hw = &hlds[w][0];

    for (int t = 0; t < 4; ++t) {
        const int b0 = w * 64 + t * 16;

        // ---- per-tile geometry (16 lanes; mask folded; rij read-once -> nt) ----
        if (lane < 16) {
            const float* rp = rij + (rowbase + b0 + lane) * 3;
            const float x = __builtin_nontemporal_load(rp);
            const float y = __builtin_nontemporal_load(rp + 1);
            const float z = __builtin_nontemporal_load(rp + 2);
            const float d2 = x * x + y * y + z * z;
            const float d  = sqrtf(d2);
            const float m  = (d >= EPSF) ? 1.f : 0.f;
            const float inv = m / (d + EPSF);
            const float ir2 = m / fmaxf(d2, EPSF);
            float* gp = &geom[w][lane][0];
            gp[0] = x * inv; gp[1] = y * inv; gp[2] = z * inv;
            gp[3] = x * y * ir2;
            gp[4] = y * z * ir2;
            gp[5] = (2.f * z * z - x * x - y * y) * (ir2 * Y2C);
            gp[6] = z * x * ir2;
            gp[7] = (x * x - y * y) * (ir2 * 0.5f);
        }

        // ---- rbf A-fragment (read-once stream -> nt), shared by all 5 filters ----
        const float* rsrc = rbf + (rowbase + b0 + ln) * 32 + q * 8;
        const f32x4 ra = __builtin_nontemporal_load((const f32x4*)rsrc);
        const f32x4 rb = __builtin_nontemporal_load((const f32x4*)rsrc + 1);
        bf16x8 rbfF;
        rbfF[0] = f2bf(ra[0]); rbfF[1] = f2bf(ra[1]); rbfF[2] = f2bf(ra[2]); rbfF[3] = f2bf(ra[3]);
        rbfF[4] = f2bf(rb[0]); rbfF[5] = f2bf(rb[1]); rbfF[6] = f2bf(rb[2]); rbfF[7] = f2bf(rb[3]);

        f32x4 r0, r1, r2, r3;

        // ================= filter 0 (scalar): o0_s, o1_s, o2_s =================
        mlp(wlds + 0 * 64 * WS, hw, rbfF, b1lo0, b1hi0, b2lo0, b2hi0, q, ln, r0, r1);
        #pragma unroll
        for (int rr = 0; rr < 4; ++rr) {
            const int b = b0 + q * 4 + rr;
            #pragma unroll
            for (int h = 0; h < 2; ++h) {
                const int c = ln + h * 16;
                const float s = h ? r1[rr] : r0[rr];
                acc[h][0] = fmaf(s, in0[b * CC + c], acc[h][0]);
                const float* i1p = in1 + (b * CC + c) * 3;
                acc[h][5] = fmaf(s, i1p[0], acc[h][5]);
                acc[h][6] = fmaf(s, i1p[1], acc[h][6]);
                acc[h][7] = fmaf(s, i1p[2], acc[h][7]);
                const float* i2p = in2 + (b * CC + c) * 5;
                #pragma unroll
                for (int j = 0; j < 5; ++j)
                    acc[h][16 + j] = fmaf(s, i2p[j], acc[h][16 + j]);
            }
        }

        // ================= filters 1,2 (use in0): o1_a, o2_a =================
        mlp(wlds + 1 * 64 * WS, hw, rbfF, b1lo1, b1hi1, b2lo1, b2hi1, q, ln, r0, r1);
        mlp(wlds + 2 * 64 * WS, hw, rbfF, b1lo2, b1hi2, b2lo2, b2hi2, q, ln, r2, r3);
        #pragma unroll
        for (int rr = 0; rr < 4; ++rr) {
            const int p = q * 4 + rr;
            const int b = b0 + p;
            const float4 g0 = *(const float4*)&geom[w][p][0];
            const float4 g1 = *(const float4*)&geom[w][p][4];
            #pragma unroll
            for (int h = 0; h < 2; ++h) {
                const int c = ln + h * 16;
                const float i0 = in0[b * CC + c];
                const float t01 = (h ? r1[rr] : r0[rr]) * i0;
                acc[h][2] = fmaf(t01, g0.x, acc[h][2]);
                acc[h][3] = fmaf(t01, g0.y, acc[h][3]);
                acc[h][4] = fmaf(t01, g0.z, acc[h][4]);
                const float t02 = (h ? r3[rr] : r2[rr]) * i0;
                acc[h][11] = fmaf(t02, g0.w, acc[h][11]);
                acc[h][12] = fmaf(t02, g1.x, acc[h][12]);
                acc[h][13] = fmaf(t02, g1.y, acc[h][13]);
                acc[h][14] = fmaf(t02, g1.z, acc[h][14]);
                acc[h][15] = fmaf(t02, g1.w, acc[h][15]);
            }
        }

        // ================= filters 3,4 (use in1): o0_b, o1_c =================
        mlp(wlds + 3 * 64 * WS, hw, rbfF, b1lo3, b1hi3, b2lo3, b2hi3, q, ln, r0, r1);
        mlp(wlds + 4 * 64 * WS, hw, rbfF, b1lo4, b1hi4, b2lo4, b2hi4, q, ln, r2, r3);
        #pragma unroll
        for (int rr = 0; rr < 4; ++rr) {
            const int p = q * 4 + rr;
            const int b = b0 + p;
            const float4 g0 = *(const float4*)&geom[w][p][0];
            const float ux = g0.x, uy = g0.y, uz = g0.z;
            #pragma unroll
            for (int h = 0; h < 2; ++h) {
                const int c = ln + h * 16;
                const float* i1p = in1 + (b * CC + c) * 3;
                const float i10 = i1p[0], i11 = i1p[1], i12 = i1p[2];
                const float s10 = h ? r1[rr] : r0[rr];
                const float s11 = h ? r3[rr] : r2[rr];
                const float dt = fmaf(uz, i12, fmaf(uy, i11, ux * i10));
                acc[h][1] = fmaf(s10, dt, acc[h][1]);
                const float cx = fmaf(uy, i12, -(uz * i11));
                const float cy = fmaf(uz, i10, -(ux * i12));
                const float cz = fmaf(ux, i11, -(uy * i10));
                acc[h][8]  = fmaf(s11, cx, acc[h][8]);
                acc[h][9]  = fmaf(s11, cy, acc[h][9]);
                acc[h][10] = fmaf(s11, cz, acc[h][10]);
            }
        }
    }

    // ---- cross-wave reduction; reuse wlds space (dead now) as fp32 red buffer ----
    __syncthreads();                       // all waves done reading wlds
    float* red = (float*)wlds;             // [8][21][32] = 21504 B <= 25600 B
    #pragma unroll
    for (int h = 0; h < 2; ++h) {
        #pragma unroll
        for (int cmp = 0; cmp < 21; ++cmp) {
            float v = acc[h][cmp];
            v += __shfl_down(v, 32);
            v += __shfl_down(v, 16);
            if (lane < 16) red[(w * 21 + cmp) * 32 + ln + h * 16] = v;
        }
    }
    __syncthreads();

    const int NC = NN * CC;
    for (int e = tid; e < 21 * 32; e += 512) {
        const int cmp = e >> 5, c = e & 31;
        float s = 0.f;
        #pragma unroll
        for (int g = 0; g < 8; ++g) s += red[(g * 21 + cmp) * 32 + c];
        int idx;
        if (cmp == 0)       idx = a * CC + c;                                       // o0_s
        else if (cmp == 1)  idx = NC + a * CC + c;                                  // o0_b
        else if (cmp < 5)   idx = 2 * NC + (a * CC + c) * 3 + (cmp - 2);            // o1_a
        else if (cmp < 8)   idx = 2 * NC + 3 * NC + (a * CC + c) * 3 + (cmp - 5);   // o1_s
        else if (cmp < 11)  idx = 2 * NC + 6 * NC + (a * CC + c) * 3 + (cmp - 8);   // o1_c
        else if (cmp < 16)  idx = 11 * NC + (a * CC + c) * 5 + (cmp - 11);          // o2_a
        else                idx = 11 * NC + 5 * NC + (a * CC + c) * 5 + (cmp - 16); // o2_s
        out[idx] = s;
    }
}

extern "C" void kernel_launch(void* const* d_in, const int* in_sizes, int n_in,
                              void* d_out, int out_size, void* d_ws, size_t ws_size,
                              hipStream_t stream) {
    const float* in0 = (const float*)d_in[0];
    const float* in1 = (const float*)d_in[1];
    const float* in2 = (const float*)d_in[2];
    const float* rbf = (const float*)d_in[3];
    const float* rij = (const float*)d_in[4];

    hipLaunchKernelGGL(tfn_mfma, dim3(NN), dim3(512), 0, stream,
                       in0, in1, in2, rbf, rij,
                       (const float*)d_in[5],  (const float*)d_in[6],
                       (const float*)d_in[7],  (const float*)d_in[8],
                       (const float*)d_in[9],  (const float*)d_in[10],
                       (const float*)d_in[11], (const float*)d_in[12],
                       (const float*)d_in[13], (const float*)d_in[14],
                       (const float*)d_in[15], (const float*)d_in[16],
                       (const float*)d_in[17], (const float*)d_in[18],
                       (const float*)d_in[19], (const float*)d_in[20],
                       (const float*)d_in[21], (const float*)d_in[22],
                       (const float*)d_in[23], (const float*)d_in[24],
                       (float*)d_out);
}

// Round 7
// 82.697 us; speedup vs baseline: 2.2331x; 2.0923x over previous
//
#include <hip/hip_runtime.h>
#include <math.h>

#define NN 512
#define CC 32
#define EPSF 1e-8f
#define WS 40   // shorts per LDS row

typedef __attribute__((ext_vector_type(8))) short bf16x8;
typedef __attribute__((ext_vector_type(4))) float f32x4;

// fp32 -> bf16 bits, round-to-nearest-even
__device__ __forceinline__ short f2bf(float f) {
    unsigned u = __float_as_uint(f);
    u += 0x7fffu + ((u >> 16) & 1u);
    return (short)(u >> 16);
}

// Stage filter F's two 32x32 weight matrices as bf16 into LDS (compile-time F).
#define STAGE_F(F, W1P, W2P)                                                   \
    {                                                                          \
        const int n0 = tid >> 5, k0 = tid & 31;                                \
        wlds[(((F) * 2 + 0) * 32 + n0) * WS + k0]      = f2bf((W1P)[tid]);     \
        wlds[(((F) * 2 + 0) * 32 + n0 + 16) * WS + k0] = f2bf((W1P)[tid+512]); \
        wlds[(((F) * 2 + 1) * 32 + n0) * WS + k0]      = f2bf((W2P)[tid]);     \
        wlds[(((F) * 2 + 1) * 32 + n0 + 16) * WS + k0] = f2bf((W2P)[tid+512]); \
    }

// One radial MLP (2 layers, 16 pairs x 32 ch) via 4 MFMAs. All names macro-local.
#define MLP(WOFF, B1L, B1H, B2L, B2H, R0, R1)                                      \
    {                                                                              \
        const bf16x8 w1loM = *(const bf16x8*)&wlds[(WOFF) + ln * WS + q * 8];      \
        const bf16x8 w1hiM = *(const bf16x8*)&wlds[(WOFF) + (16 + ln) * WS + q * 8]; \
        f32x4 d0M = { (B1L), (B1L), (B1L), (B1L) };                                \
        f32x4 d1M = { (B1H), (B1H), (B1H), (B1H) };                                \
        d0M = __builtin_amdgcn_mfma_f32_16x16x32_bf16(rbfF, w1loM, d0M, 0, 0, 0);  \
        d1M = __builtin_amdgcn_mfma_f32_16x16x32_bf16(rbfF, w1hiM, d1M, 0, 0, 0);  \
        hlds[w][(q * 4 + 0) * WS + ln]      = f2bf(fmaxf(d0M[0], 0.f));            \
        hlds[w][(q * 4 + 1) * WS + ln]      = f2bf(fmaxf(d0M[1], 0.f));            \
        hlds[w][(q * 4 + 2) * WS + ln]      = f2bf(fmaxf(d0M[2], 0.f));            \
        hlds[w][(q * 4 + 3) * WS + ln]      = f2bf(fmaxf(d0M[3], 0.f));            \
        hlds[w][(q * 4 + 0) * WS + 16 + ln] = f2bf(fmaxf(d1M[0], 0.f));            \
        hlds[w][(q * 4 + 1) * WS + 16 + ln] = f2bf(fmaxf(d1M[1], 0.f));            \
        hlds[w][(q * 4 + 2) * WS + 16 + ln] = f2bf(fmaxf(d1M[2], 0.f));            \
        hlds[w][(q * 4 + 3) * WS + 16 + ln] = f2bf(fmaxf(d1M[3], 0.f));            \
        const bf16x8 hFM   = *(const bf16x8*)&hlds[w][ln * WS + q * 8];            \
        const bf16x8 w2loM = *(const bf16x8*)&wlds[(WOFF) + (32 + ln) * WS + q * 8]; \
        const bf16x8 w2hiM = *(const bf16x8*)&wlds[(WOFF) + (48 + ln) * WS + q * 8]; \
        f32x4 e0M = { (B2L), (B2L), (B2L), (B2L) };                                \
        f32x4 e1M = { (B2H), (B2H), (B2H), (B2H) };                                \
        R0 = __builtin_amdgcn_mfma_f32_16x16x32_bf16(hFM, w2loM, e0M, 0, 0, 0);    \
        R1 = __builtin_amdgcn_mfma_f32_16x16x32_bf16(hFM, w2hiM, e1M, 0, 0, 0);    \
    }

// Filter-0 aggregation for one (pair rr, channel C) slot.
#define AGG0(RR, RV, A0, A5, A6, A7, A16, A17, A18, A19, A20, C)               \
    {                                                                          \
        const int bA = b0 + q * 4 + (RR);                                      \
        const float sA = (RV)[(RR)];                                           \
        A0 = fmaf(sA, in0[bA * CC + (C)], A0);                                 \
        const float* i1A = in1 + (bA * CC + (C)) * 3;                          \
        A5 = fmaf(sA, i1A[0], A5);                                             \
        A6 = fmaf(sA, i1A[1], A6);                                             \
        A7 = fmaf(sA, i1A[2], A7);                                             \
        const float* i2A = in2 + (bA * CC + (C)) * 5;                          \
        A16 = fmaf(sA, i2A[0], A16);                                           \
        A17 = fmaf(sA, i2A[1], A17);                                           \
        A18 = fmaf(sA, i2A[2], A18);                                           \
        A19 = fmaf(sA, i2A[3], A19);                                           \
        A20 = fmaf(sA, i2A[4], A20);                                           \
    }

// Filters 1,2 aggregation (needs gxA..g4A in scope).
#define AGG12(RR, RV1, RV2, A2, A3, A4, A11, A12, A13, A14, A15, C)            \
    {                                                                          \
        const int bA = b0 + q * 4 + (RR);                                      \
        const float i0A = in0[bA * CC + (C)];                                  \
        const float t1A = (RV1)[(RR)] * i0A;                                   \
        A2 = fmaf(t1A, gxA, A2);                                               \
        A3 = fmaf(t1A, gyA, A3);                                               \
        A4 = fmaf(t1A, gzA, A4);                                               \
        const float t2A = (RV2)[(RR)] * i0A;                                   \
        A11 = fmaf(t2A, g0A, A11);                                             \
        A12 = fmaf(t2A, g1A, A12);                                             \
        A13 = fmaf(t2A, g2A, A13);                                             \
        A14 = fmaf(t2A, g3A, A14);                                             \
        A15 = fmaf(t2A, g4A, A15);                                             \
    }

#define AGG12RR(RR)                                                            \
    {                                                                          \
        const f32x4 gA = *(const f32x4*)&geom[w][q * 4 + (RR)][0];             \
        const f32x4 gB = *(const f32x4*)&geom[w][q * 4 + (RR)][4];             \
        const float gxA = gA[0], gyA = gA[1], gzA = gA[2];                     \
        const float g0A = gA[3], g1A = gB[0], g2A = gB[1], g3A = gB[2], g4A = gB[3]; \
        AGG12((RR), r0, r2, aL2, aL3, aL4, aL11, aL12, aL13, aL14, aL15, ln)   \
        AGG12((RR), r1, r3, aH2, aH3, aH4, aH11, aH12, aH13, aH14, aH15, 16 + ln) \
    }

// Filters 3,4 aggregation (needs gxA..gzA in scope).
#define AGG34(RR, RV1, RV2, A1, A8, A9, A10, C)                                \
    {                                                                          \
        const int bA = b0 + q * 4 + (RR);                                      \
        const float* i1A = in1 + (bA * CC + (C)) * 3;                          \
        const float x1A = i1A[0], y1A = i1A[1], z1A = i1A[2];                  \
        const float dtA = fmaf(gzA, z1A, fmaf(gyA, y1A, gxA * x1A));           \
        A1 = fmaf((RV1)[(RR)], dtA, A1);                                       \
        const float cxA = fmaf(gyA, z1A, -(gzA * y1A));                        \
        const float cyA = fmaf(gzA, x1A, -(gxA * z1A));                        \
        const float czA = fmaf(gxA, y1A, -(gyA * x1A));                        \
        A8  = fmaf((RV2)[(RR)], cxA, A8);                                      \
        A9  = fmaf((RV2)[(RR)], cyA, A9);                                      \
        A10 = fmaf((RV2)[(RR)], czA, A10);                                     \
    }

#define AGG34RR(RR)                                                            \
    {                                                                          \
        const f32x4 gA = *(const f32x4*)&geom[w][q * 4 + (RR)][0];             \
        const float gxA = gA[0], gyA = gA[1], gzA = gA[2];                     \
        AGG34((RR), r0, r2, aL1, aL8, aL9, aL10, ln)                           \
        AGG34((RR), r1, r3, aH1, aH8, aH9, aH10, 16 + ln)                      \
    }

#define RED1(CMP, VL, VH)                                                      \
    {                                                                          \
        float vR = (VL);                                                       \
        vR += __shfl_down(vR, 32);                                             \
        vR += __shfl_down(vR, 16);                                             \
        float uR = (VH);                                                       \
        uR += __shfl_down(uR, 32);                                             \
        uR += __shfl_down(uR, 16);                                             \
        if (lane < 16) {                                                       \
            red[(w * 21 + (CMP)) * 32 + ln]      = vR;                         \
            red[(w * 21 + (CMP)) * 32 + 16 + ln] = uR;                         \
        }                                                                      \
    }

__global__ __launch_bounds__(512, 2) void tfn_mfma(
    const float* __restrict__ in0,   // [N,C,1]
    const float* __restrict__ in1,   // [N,C,3]
    const float* __restrict__ in2,   // [N,C,5]
    const float* __restrict__ rbf,   // [N,N,32]
    const float* __restrict__ rij,   // [N,N,3]
    const float* __restrict__ w1_0, const float* __restrict__ b1_0,
    const float* __restrict__ w2_0, const float* __restrict__ b2_0,
    const float* __restrict__ w1_1, const float* __restrict__ b1_1,
    const float* __restrict__ w2_1, const float* __restrict__ b2_1,
    const float* __restrict__ w1_2, const float* __restrict__ b1_2,
    const float* __restrict__ w2_2, const float* __restrict__ b2_2,
    const float* __restrict__ w1_3, const float* __restrict__ b1_3,
    const float* __restrict__ w2_3, const float* __restrict__ b2_3,
    const float* __restrict__ w1_4, const float* __restrict__ b1_4,
    const float* __restrict__ w2_4, const float* __restrict__ b2_4,
    float* __restrict__ out)
{
    const int a    = blockIdx.x;
    const int tid  = threadIdx.x;
    const int w    = tid >> 6;     // wave 0..7
    const int lane = tid & 63;
    const int q    = lane >> 4;
    const int ln   = lane & 15;

    __shared__ short wlds[5 * 2 * 32 * WS];  // weights bf16; aliased as `red` later
    __shared__ short hlds[8][16 * WS];       // per-wave h transpose tile
    __shared__ float geom[8][16][8];         // ux,uy,uz,y20..y24 (mask folded)

    STAGE_F(0, w1_0, w2_0)
    STAGE_F(1, w1_1, w2_1)
    STAGE_F(2, w1_2, w2_2)
    STAGE_F(3, w1_3, w2_3)
    STAGE_F(4, w1_4, w2_4)

    const float b1lo0 = b1_0[ln], b1hi0 = b1_0[16 + ln], b2lo0 = b2_0[ln], b2hi0 = b2_0[16 + ln];
    const float b1lo1 = b1_1[ln], b1hi1 = b1_1[16 + ln], b2lo1 = b2_1[ln], b2hi1 = b2_1[16 + ln];
    const float b1lo2 = b1_2[ln], b1hi2 = b1_2[16 + ln], b2lo2 = b2_2[ln], b2hi2 = b2_2[16 + ln];
    const float b1lo3 = b1_3[ln], b1hi3 = b1_3[16 + ln], b2lo3 = b2_3[ln], b2hi3 = b2_3[16 + ln];
    const float b1lo4 = b1_4[ln], b1hi4 = b1_4[16 + ln], b2lo4 = b2_4[ln], b2hi4 = b2_4[16 + ln];
    __syncthreads();

    // 42 named scalar accumulators (no private arrays anywhere in this kernel)
    float aL0 = 0.f, aL1 = 0.f, aL2 = 0.f, aL3 = 0.f, aL4 = 0.f, aL5 = 0.f, aL6 = 0.f;
    float aL7 = 0.f, aL8 = 0.f, aL9 = 0.f, aL10 = 0.f, aL11 = 0.f, aL12 = 0.f, aL13 = 0.f;
    float aL14 = 0.f, aL15 = 0.f, aL16 = 0.f, aL17 = 0.f, aL18 = 0.f, aL19 = 0.f, aL20 = 0.f;
    float aH0 = 0.f, aH1 = 0.f, aH2 = 0.f, aH3 = 0.f, aH4 = 0.f, aH5 = 0.f, aH6 = 0.f;
    float aH7 = 0.f, aH8 = 0.f, aH9 = 0.f, aH10 = 0.f, aH11 = 0.f, aH12 = 0.f, aH13 = 0.f;
    float aH14 = 0.f, aH15 = 0.f, aH16 = 0.f, aH17 = 0.f, aH18 = 0.f, aH19 = 0.f, aH20 = 0.f;

    const size_t rowbase = (size_t)a * NN;
    const float Y2C = 0.28867513459481287f;  // 1/(2*sqrt(3))

    #pragma unroll 1
    for (int t = 0; t < 4; ++t) {
        const int b0 = w * 64 + t * 16;

        // ---- per-tile geometry (16 lanes; mask folded; rij read-once -> nt) ----
        if (lane < 16) {
            const float* rp = rij + (rowbase + b0 + lane) * 3;
            const float x = __builtin_nontemporal_load(rp);
            const float y = __builtin_nontemporal_load(rp + 1);
            const float z = __builtin_nontemporal_load(rp + 2);
            const float d2 = x * x + y * y + z * z;
            const float d  = sqrtf(d2);
            const float m  = (d >= EPSF) ? 1.f : 0.f;
            const float inv = m / (d + EPSF);
            const float ir2 = m / fmaxf(d2, EPSF);
            float* gp = &geom[w][lane][0];
            gp[0] = x * inv; gp[1] = y * inv; gp[2] = z * inv;
            gp[3] = x * y * ir2;
            gp[4] = y * z * ir2;
            gp[5] = (2.f * z * z - x * x - y * y) * (ir2 * Y2C);
            gp[6] = z * x * ir2;
            gp[7] = (x * x - y * y) * (ir2 * 0.5f);
        }

        // ---- rbf A-fragment (read-once stream -> nt), shared by all 5 filters ----
        const float* rsrc = rbf + (rowbase + b0 + ln) * 32 + q * 8;
        const f32x4 ra = __builtin_nontemporal_load((const f32x4*)rsrc);
        const f32x4 rb = __builtin_nontemporal_load((const f32x4*)rsrc + 1);
        bf16x8 rbfF;
        rbfF[0] = f2bf(ra[0]); rbfF[1] = f2bf(ra[1]); rbfF[2] = f2bf(ra[2]); rbfF[3] = f2bf(ra[3]);
        rbfF[4] = f2bf(rb[0]); rbfF[5] = f2bf(rb[1]); rbfF[6] = f2bf(rb[2]); rbfF[7] = f2bf(rb[3]);

        f32x4 r0, r1, r2, r3;

        // ================= filter 0 (scalar): o0_s, o1_s, o2_s =================
        MLP(0 * 64 * WS, b1lo0, b1hi0, b2lo0, b2hi0, r0, r1)
        AGG0(0, r0, aL0, aL5, aL6, aL7, aL16, aL17, aL18, aL19, aL20, ln)
        AGG0(0, r1, aH0, aH5, aH6, aH7, aH16, aH17, aH18, aH19, aH20, 16 + ln)
        AGG0(1, r0, aL0, aL5, aL6, aL7, aL16, aL17, aL18, aL19, aL20, ln)
        AGG0(1, r1, aH0, aH5, aH6, aH7, aH16, aH17, aH18, aH19, aH20, 16 + ln)
        AGG0(2, r0, aL0, aL5, aL6, aL7, aL16, aL17, aL18, aL19, aL20, ln)
        AGG0(2, r1, aH0, aH5, aH6, aH7, aH16, aH17, aH18, aH19, aH20, 16 + ln)
        AGG0(3, r0, aL0, aL5, aL6, aL7, aL16, aL17, aL18, aL19, aL20, ln)
        AGG0(3, r1, aH0, aH5, aH6, aH7, aH16, aH17, aH18, aH19, aH20, 16 + ln)
        __builtin_amdgcn_sched_barrier(0);

        // ================= filters 1,2 (use in0): o1_a, o2_a =================
        MLP(1 * 64 * WS, b1lo1, b1hi1, b2lo1, b2hi1, r0, r1)
        MLP(2 * 64 * WS, b1lo2, b1hi2, b2lo2, b2hi2, r2, r3)
        AGG12RR(0)
        AGG12RR(1)
        AGG12RR(2)
        AGG12RR(3)
        __builtin_amdgcn_sched_barrier(0);

        // ================= filters 3,4 (use in1): o0_b, o1_c =================
        MLP(3 * 64 * WS, b1lo3, b1hi3, b2lo3, b2hi3, r0, r1)
        MLP(4 * 64 * WS, b1lo4, b1hi4, b2lo4, b2hi4, r2, r3)
        AGG34RR(0)
        AGG34RR(1)
        AGG34RR(2)
        AGG34RR(3)
        __builtin_amdgcn_sched_barrier(0);
    }

    // ---- cross-wave reduction; reuse wlds space (dead now) as fp32 red buffer ----
    __syncthreads();                       // all waves done reading wlds
    float* red = (float*)wlds;             // [8][21][32] = 21504 B <= 25600 B
    RED1(0,  aL0,  aH0)  RED1(1,  aL1,  aH1)  RED1(2,  aL2,  aH2)
    RED1(3,  aL3,  aH3)  RED1(4,  aL4,  aH4)  RED1(5,  aL5,  aH5)
    RED1(6,  aL6,  aH6)  RED1(7,  aL7,  aH7)  RED1(8,  aL8,  aH8)
    RED1(9,  aL9,  aH9)  RED1(10, aL10, aH10) RED1(11, aL11, aH11)
    RED1(12, aL12, aH12) RED1(13, aL13, aH13) RED1(14, aL14, aH14)
    RED1(15, aL15, aH15) RED1(16, aL16, aH16) RED1(17, aL17, aH17)
    RED1(18, aL18, aH18) RED1(19, aL19, aH19) RED1(20, aL20, aH20)
    __syncthreads();

    const int NC = NN * CC;
    for (int e = tid; e < 21 * 32; e += 512) {
        const int cmp = e >> 5, c = e & 31;
        float s = 0.f;
        #pragma unroll
        for (int g = 0; g < 8; ++g) s += red[(g * 21 + cmp) * 32 + c];
        int idx;
        if (cmp == 0)       idx = a * CC + c;                                       // o0_s
        else if (cmp == 1)  idx = NC + a * CC + c;                                  // o0_b
        else if (cmp < 5)   idx = 2 * NC + (a * CC + c) * 3 + (cmp - 2);            // o1_a
        else if (cmp < 8)   idx = 2 * NC + 3 * NC + (a * CC + c) * 3 + (cmp - 5);   // o1_s
        else if (cmp < 11)  idx = 2 * NC + 6 * NC + (a * CC + c) * 3 + (cmp - 8);   // o1_c
        else if (cmp < 16)  idx = 11 * NC + (a * CC + c) * 5 + (cmp - 11);          // o2_a
        else                idx = 11 * NC + 5 * NC + (a * CC + c) * 5 + (cmp - 16); // o2_s
        out[idx] = s;
    }
}

extern "C" void kernel_launch(void* const* d_in, const int* in_sizes, int n_in,
                              void* d_out, int out_size, void* d_ws, size_t ws_size,
                              hipStream_t stream) {
    const float* in0 = (const float*)d_in[0];
    const float* in1 = (const float*)d_in[1];
    const float* in2 = (const float*)d_in[2];
    const float* rbf = (const float*)d_in[3];
    const float* rij = (const float*)d_in[4];

    hipLaunchKernelGGL(tfn_mfma, dim3(NN), dim3(512), 0, stream,
                       in0, in1, in2, rbf, rij,
                       (const float*)d_in[5],  (const float*)d_in[6],
                       (const float*)d_in[7],  (const float*)d_in[8],
                       (const float*)d_in[9],  (const float*)d_in[10],
                       (const float*)d_in[11], (const float*)d_in[12],
                       (const float*)d_in[13], (const float*)d_in[14],
                       (const float*)d_in[15], (const float*)d_in[16],
                       (const float*)d_in[17], (const float*)d_in[18],
                       (const float*)d_in[19], (const float*)d_in[20],
                       (const float*)d_in[21], (const float*)d_in[22],
                       (const float*)d_in[23], (const float*)d_in[24],
                       (float*)d_out);
}

// Round 8
// 48.802 us; speedup vs baseline: 3.7841x; 1.6945x over previous
//
#include <hip/hip_runtime.h>
#include <math.h>

#define NN 512
#define CC 32
#define EPSF 1e-8f
#define WS 40   // shorts per LDS row

typedef __attribute__((ext_vector_type(8))) short bf16x8;
typedef __attribute__((ext_vector_type(4))) float f32x4;

// fp32 -> bf16 bits, round-to-nearest-even
__device__ __forceinline__ short f2bf(float f) {
    unsigned u = __float_as_uint(f);
    u += 0x7fffu + ((u >> 16) & 1u);
    return (short)(u >> 16);
}

// Stage filter F's two 32x32 weight matrices as bf16 into LDS (compile-time F).
#define STAGE_F(F, W1P, W2P)                                                   \
    {                                                                          \
        const int n0 = tid >> 5, k0 = tid & 31;                                \
        wlds[(((F) * 2 + 0) * 32 + n0) * WS + k0]      = f2bf((W1P)[tid]);     \
        wlds[(((F) * 2 + 0) * 32 + n0 + 16) * WS + k0] = f2bf((W1P)[tid+512]); \
        wlds[(((F) * 2 + 1) * 32 + n0) * WS + k0]      = f2bf((W2P)[tid]);     \
        wlds[(((F) * 2 + 1) * 32 + n0 + 16) * WS + k0] = f2bf((W2P)[tid+512]); \
    }

// One radial MLP for 16 pairs; layer1 full hidden (2 MFMA), layer2 only this
// wave's 16-channel half (1 MFMA). Result R[rr] = rad[p=4q+rr][cw].
#define MLP3(WOFF, B1L, B1H, B2V, R)                                               \
    {                                                                              \
        const bf16x8 w1loM = *(const bf16x8*)&wlds[(WOFF) + ln * WS + q * 8];      \
        const bf16x8 w1hiM = *(const bf16x8*)&wlds[(WOFF) + (16 + ln) * WS + q * 8]; \
        f32x4 d0M = { (B1L), (B1L), (B1L), (B1L) };                                \
        f32x4 d1M = { (B1H), (B1H), (B1H), (B1H) };                                \
        d0M = __builtin_amdgcn_mfma_f32_16x16x32_bf16(rbfF, w1loM, d0M, 0, 0, 0);  \
        d1M = __builtin_amdgcn_mfma_f32_16x16x32_bf16(rbfF, w1hiM, d1M, 0, 0, 0);  \
        hlds[w][(q * 4 + 0) * WS + ln]      = f2bf(fmaxf(d0M[0], 0.f));            \
        hlds[w][(q * 4 + 1) * WS + ln]      = f2bf(fmaxf(d0M[1], 0.f));            \
        hlds[w][(q * 4 + 2) * WS + ln]      = f2bf(fmaxf(d0M[2], 0.f));            \
        hlds[w][(q * 4 + 3) * WS + ln]      = f2bf(fmaxf(d0M[3], 0.f));            \
        hlds[w][(q * 4 + 0) * WS + 16 + ln] = f2bf(fmaxf(d1M[0], 0.f));            \
        hlds[w][(q * 4 + 1) * WS + 16 + ln] = f2bf(fmaxf(d1M[1], 0.f));            \
        hlds[w][(q * 4 + 2) * WS + 16 + ln] = f2bf(fmaxf(d1M[2], 0.f));            \
        hlds[w][(q * 4 + 3) * WS + 16 + ln] = f2bf(fmaxf(d1M[3], 0.f));            \
        const bf16x8 hFM = *(const bf16x8*)&hlds[w][ln * WS + q * 8];              \
        const bf16x8 w2M = *(const bf16x8*)&wlds[(WOFF) + (32 + ch0 + ln) * WS + q * 8]; \
        f32x4 eM = { (B2V), (B2V), (B2V), (B2V) };                                 \
        R = __builtin_amdgcn_mfma_f32_16x16x32_bf16(hFM, w2M, eM, 0, 0, 0);        \
    }

// Filter-0 aggregation, pair rr, this wave's channel cw.
#define AGG0R(RR)                                                              \
    {                                                                          \
        const int bA = b0 + q * 4 + (RR);                                      \
        const float sA = r0[(RR)];                                             \
        a0 = fmaf(sA, in0[bA * CC + cw], a0);                                  \
        const float* i1A = in1 + (bA * CC + cw) * 3;                           \
        a5 = fmaf(sA, i1A[0], a5);                                             \
        a6 = fmaf(sA, i1A[1], a6);                                             \
        a7 = fmaf(sA, i1A[2], a7);                                             \
        const float* i2A = in2 + (bA * CC + cw) * 5;                           \
        a16 = fmaf(sA, i2A[0], a16);                                           \
        a17 = fmaf(sA, i2A[1], a17);                                           \
        a18 = fmaf(sA, i2A[2], a18);                                           \
        a19 = fmaf(sA, i2A[3], a19);                                           \
        a20 = fmaf(sA, i2A[4], a20);                                           \
    }

// Filters 1,2 aggregation (r0 = F1 rad, r1 = F2 rad).
#define AGG12R(RR)                                                             \
    {                                                                          \
        const int bA = b0 + q * 4 + (RR);                                      \
        const f32x4 gA = *(const f32x4*)&geom[w][q * 4 + (RR)][0];             \
        const f32x4 gB = *(const f32x4*)&geom[w][q * 4 + (RR)][4];             \
        const float i0A = in0[bA * CC + cw];                                   \
        const float t1A = r0[(RR)] * i0A;                                      \
        a2 = fmaf(t1A, gA[0], a2);                                             \
        a3 = fmaf(t1A, gA[1], a3);                                             \
        a4 = fmaf(t1A, gA[2], a4);                                             \
        const float t2A = r1[(RR)] * i0A;                                      \
        a11 = fmaf(t2A, gA[3], a11);                                           \
        a12 = fmaf(t2A, gB[0], a12);                                           \
        a13 = fmaf(t2A, gB[1], a13);                                           \
        a14 = fmaf(t2A, gB[2], a14);                                           \
        a15 = fmaf(t2A, gB[3], a15);                                           \
    }

// Filters 3,4 aggregation (r0 = F3 rad, r1 = F4 rad).
#define AGG34R(RR)                                                             \
    {                                                                          \
        const int bA = b0 + q * 4 + (RR);                                      \
        const f32x4 gA = *(const f32x4*)&geom[w][q * 4 + (RR)][0];             \
        const float gxA = gA[0], gyA = gA[1], gzA = gA[2];                     \
        const float* i1A = in1 + (bA * CC + cw) * 3;                           \
        const float x1A = i1A[0], y1A = i1A[1], z1A = i1A[2];                  \
        const float dtA = fmaf(gzA, z1A, fmaf(gyA, y1A, gxA * x1A));           \
        a1 = fmaf(r0[(RR)], dtA, a1);                                          \
        const float cxA = fmaf(gyA, z1A, -(gzA * y1A));                        \
        const float cyA = fmaf(gzA, x1A, -(gxA * z1A));                        \
        const float czA = fmaf(gxA, y1A, -(gyA * x1A));                        \
        a8  = fmaf(r1[(RR)], cxA, a8);                                         \
        a9  = fmaf(r1[(RR)], cyA, a9);                                         \
        a10 = fmaf(r1[(RR)], czA, a10);                                        \
    }

#define RED(CMP, V)                                                            \
    {                                                                          \
        float vR = (V);                                                        \
        vR += __shfl_down(vR, 32);                                             \
        vR += __shfl_down(vR, 16);                                             \
        if (lane < 16) red[(w * 21 + (CMP)) * 16 + ln] = vR;                   \
    }

__global__ __launch_bounds__(512, 2) void tfn_mfma(
    const float* __restrict__ in0,   // [N,C,1]
    const float* __restrict__ in1,   // [N,C,3]
    const float* __restrict__ in2,   // [N,C,5]
    const float* __restrict__ rbf,   // [N,N,32]
    const float* __restrict__ rij,   // [N,N,3]
    const float* __restrict__ w1_0, const float* __restrict__ b1_0,
    const float* __restrict__ w2_0, const float* __restrict__ b2_0,
    const float* __restrict__ w1_1, const float* __restrict__ b1_1,
    const float* __restrict__ w2_1, const float* __restrict__ b2_1,
    const float* __restrict__ w1_2, const float* __restrict__ b1_2,
    const float* __restrict__ w2_2, const float* __restrict__ b2_2,
    const float* __restrict__ w1_3, const float* __restrict__ b1_3,
    const float* __restrict__ w2_3, const float* __restrict__ b2_3,
    const float* __restrict__ w1_4, const float* __restrict__ b1_4,
    const float* __restrict__ w2_4, const float* __restrict__ b2_4,
    float* __restrict__ out)
{
    const int a    = blockIdx.x;
    const int tid  = threadIdx.x;
    const int w    = tid >> 6;     // wave 0..7 = (b-range pair) * 2 + channel-half
    const int lane = tid & 63;
    const int q    = lane >> 4;
    const int ln   = lane & 15;
    const int ch0  = (w & 1) * 16; // this wave's channel-half base
    const int cw   = ch0 + ln;     // this lane's channel

    __shared__ short wlds[5 * 2 * 32 * WS];  // weights bf16; aliased as `red` later
    __shared__ short hlds[8][16 * WS];       // per-wave h transpose tile
    __shared__ float geom[8][16][8];         // ux,uy,uz,y20..y24 (mask folded)

    STAGE_F(0, w1_0, w2_0)
    STAGE_F(1, w1_1, w2_1)
    STAGE_F(2, w1_2, w2_2)
    STAGE_F(3, w1_3, w2_3)
    STAGE_F(4, w1_4, w2_4)

    // layer-1 biases: full hidden (both halves); layer-2 bias: own half only
    const float b1lo0 = b1_0[ln], b1hi0 = b1_0[16 + ln], b2v0 = b2_0[cw];
    const float b1lo1 = b1_1[ln], b1hi1 = b1_1[16 + ln], b2v1 = b2_1[cw];
    const float b1lo2 = b1_2[ln], b1hi2 = b1_2[16 + ln], b2v2 = b2_2[cw];
    const float b1lo3 = b1_3[ln], b1hi3 = b1_3[16 + ln], b2v3 = b2_3[cw];
    const float b1lo4 = b1_4[ln], b1hi4 = b1_4[16 + ln], b2v4 = b2_4[cw];
    __syncthreads();

    // 21 named scalar accumulators
    float a0 = 0.f, a1 = 0.f, a2 = 0.f, a3 = 0.f, a4 = 0.f, a5 = 0.f, a6 = 0.f;
    float a7 = 0.f, a8 = 0.f, a9 = 0.f, a10 = 0.f, a11 = 0.f, a12 = 0.f, a13 = 0.f;
    float a14 = 0.f, a15 = 0.f, a16 = 0.f, a17 = 0.f, a18 = 0.f, a19 = 0.f, a20 = 0.f;

    const size_t rowbase = (size_t)a * NN;
    const float Y2C = 0.28867513459481287f;  // 1/(2*sqrt(3))
    const int pairb = (w >> 1) * 128;        // this wave-pair's b range [pairb, pairb+128)

    // software prefetch of the first rbf fragment
    const float* rbase = rbf + (rowbase + pairb + ln) * 32 + q * 8;
    f32x4 curA = *(const f32x4*)rbase;
    f32x4 curB = *(const f32x4*)(rbase + 4);

    #pragma unroll 1
    for (int t = 0; t < 8; ++t) {
        const int b0 = pairb + t * 16;

        // convert current rbf fragment, then prefetch next tile's
        bf16x8 rbfF;
        rbfF[0] = f2bf(curA[0]); rbfF[1] = f2bf(curA[1]);
        rbfF[2] = f2bf(curA[2]); rbfF[3] = f2bf(curA[3]);
        rbfF[4] = f2bf(curB[0]); rbfF[5] = f2bf(curB[1]);
        rbfF[6] = f2bf(curB[2]); rbfF[7] = f2bf(curB[3]);
        if (t < 7) {
            curA = *(const f32x4*)(rbase + (t + 1) * 512);
            curB = *(const f32x4*)(rbase + (t + 1) * 512 + 4);
        }

        // per-tile geometry (16 lanes; mask folded into u and y2)
        if (lane < 16) {
            const float* rp = rij + (rowbase + b0 + lane) * 3;
            const float x = rp[0], y = rp[1], z = rp[2];
            const float d2 = x * x + y * y + z * z;
            const float d  = sqrtf(d2);
            const float m  = (d >= EPSF) ? 1.f : 0.f;
            const float inv = m / (d + EPSF);
            const float ir2 = m / fmaxf(d2, EPSF);
            float* gp = &geom[w][lane][0];
            gp[0] = x * inv; gp[1] = y * inv; gp[2] = z * inv;
            gp[3] = x * y * ir2;
            gp[4] = y * z * ir2;
            gp[5] = (2.f * z * z - x * x - y * y) * (ir2 * Y2C);
            gp[6] = z * x * ir2;
            gp[7] = (x * x - y * y) * (ir2 * 0.5f);
        }

        f32x4 r0, r1;

        // filter 0 (scalar): o0_s, o1_s, o2_s
        MLP3(0 * 64 * WS, b1lo0, b1hi0, b2v0, r0)
        AGG0R(0) AGG0R(1) AGG0R(2) AGG0R(3)

        // filters 1,2 (use in0): o1_a, o2_a
        MLP3(1 * 64 * WS, b1lo1, b1hi1, b2v1, r0)
        MLP3(2 * 64 * WS, b1lo2, b1hi2, b2v2, r1)
        AGG12R(0) AGG12R(1) AGG12R(2) AGG12R(3)

        // filters 3,4 (use in1): o0_b, o1_c
        MLP3(3 * 64 * WS, b1lo3, b1hi3, b2v3, r0)
        MLP3(4 * 64 * WS, b1lo4, b1hi4, b2v4, r1)
        AGG34R(0) AGG34R(1) AGG34R(2) AGG34R(3)

        __builtin_amdgcn_sched_barrier(0);
    }

    // ---- reduce over q within wave, then over the 4 b-range pairs via LDS ----
    __syncthreads();                       // all waves done reading wlds
    float* red = (float*)wlds;             // [8][21][16] = 10752 B <= 25600 B
    RED(0,  a0)  RED(1,  a1)  RED(2,  a2)  RED(3,  a3)  RED(4,  a4)
    RED(5,  a5)  RED(6,  a6)  RED(7,  a7)  RED(8,  a8)  RED(9,  a9)
    RED(10, a10) RED(11, a11) RED(12, a12) RED(13, a13) RED(14, a14)
    RED(15, a15) RED(16, a16) RED(17, a17) RED(18, a18) RED(19, a19)
    RED(20, a20)
    __syncthreads();

    const int NC = NN * CC;
    for (int e = tid; e < 21 * 32; e += 512) {
        const int cmp = e >> 5, c = e & 31;
        const int hh = c >> 4, l2 = c & 15;
        float s = 0.f;
        #pragma unroll
        for (int p = 0; p < 4; ++p)
            s += red[((p * 2 + hh) * 21 + cmp) * 16 + l2];
        int idx;
        if (cmp == 0)       idx = a * CC + c;                                       // o0_s
        else if (cmp == 1)  idx = NC + a * CC + c;                                  // o0_b
        else if (cmp < 5)   idx = 2 * NC + (a * CC + c) * 3 + (cmp - 2);            // o1_a
        else if (cmp < 8)   idx = 2 * NC + 3 * NC + (a * CC + c) * 3 + (cmp - 5);   // o1_s
        else if (cmp < 11)  idx = 2 * NC + 6 * NC + (a * CC + c) * 3 + (cmp - 8);   // o1_c
        else if (cmp < 16)  idx = 11 * NC + (a * CC + c) * 5 + (cmp - 11);          // o2_a
        else                idx = 11 * NC + 5 * NC + (a * CC + c) * 5 + (cmp - 16); // o2_s
        out[idx] = s;
    }
}

extern "C" void kernel_launch(void* const* d_in, const int* in_sizes, int n_in,
                              void* d_out, int out_size, void* d_ws, size_t ws_size,
                              hipStream_t stream) {
    const float* in0 = (const float*)d_in[0];
    const float* in1 = (const float*)d_in[1];
    const float* in2 = (const float*)d_in[2];
    const float* rbf = (const float*)d_in[3];
    const float* rij = (const float*)d_in[4];

    hipLaunchKernelGGL(tfn_mfma, dim3(NN), dim3(512), 0, stream,
                       in0, in1, in2, rbf, rij,
                       (const float*)d_in[5],  (const float*)d_in[6],
                       (const float*)d_in[7],  (const float*)d_in[8],
                       (const float*)d_in[9],  (const float*)d_in[10],
                       (const float*)d_in[11], (const float*)d_in[12],
                       (const float*)d_in[13], (const float*)d_in[14],
                       (const float*)d_in[15], (const float*)d_in[16],
                       (const float*)d_in[17], (const float*)d_in[18],
                       (const float*)d_in[19], (const float*)d_in[20],
                       (const float*)d_in[21], (const float*)d_in[22],
                       (const float*)d_in[23], (const float*)d_in[24],
                       (float*)d_out);
}